// Round 7
// baseline (7983.695 us; speedup 1.0000x reference)
//
#include <hip/hip_runtime.h>
#include <math.h>

// resRNN forward: N=256, L=1024, inp=521 (=8 x + 1 storage + 512 hx), HID=512, OUT=1.
// Round 7: round 6's validated roof was the per-CU LDS pipe: 131 uniform-address
// ds_read_b128 per wave per step for the inps broadcast (~12.6 K cyc of the
// 17.4 K step). Replace the LDS broadcast with SGPR broadcast:
//   - lane l loads inps[4l..4l+3] -> q0 and inps[256+4l..] -> q1 (2 b128/wave)
//   - the K-sweep gets inps[k] via __builtin_amdgcn_readlane (wave-uniform ->
//     SGPR; v_fmac_f32 takes 1 SGPR operand). Broadcast cost moves from the
//     shared LDS pipe to the 4x-replicated VALU pipes (~2.5 K cyc/wave).
// Rows 512..520 (9 values) keep conventional uniform LDS reads.
// Weight residency unchanged from round 6 (proven spill-free): rows [0,128)
// AGPR via v_accvgpr asm, [128,200) LDS row-major b32, [200,520) streamed
// packed float4 (80 chunks; 78 via readlane, 2 conventional), row 520 tail.
// New roof: streamed-weight VMEM, 655 KB/step/CU at ~56-64 B/cyc.

constexpr int kN   = 256;
constexpr int kL   = 1024;
constexpr int kHin = 8;
constexpr int kHid = 512;
constexpr int kInp = kHin + 1 + kHid;        // 521
constexpr int kBlk = 512;

constexpr int RAGP  = 128;                   // W1 rows resident in AGPRs
constexpr int NAGRP = RAGP / 8;              // 16 groups of 8 rows
constexpr int RLDS  = 72;                    // W1 rows resident in LDS (144 KB)
constexpr int RRES  = RAGP + RLDS;           // 200 resident rows
constexpr int NPK   = (kInp - 1 - RRES) / 4; // 80 packed chunks of 4 streamed rows
static_assert(RLDS % 4 == 0, "LDS phase consumes 4 rows/iter");
static_assert(RRES + 4 * NPK + 1 == kInp, "row partition must cover 521 rows");
static_assert(RRES == 200 && NPK == 80, "lane arithmetic below assumes this split");

// Packed streamed weights: g_w1p[(c*512 + j)*4 + i] = W1[RRES + 4c + i][j].
__device__ __align__(16) float g_w1p[NPK * kHid * 4];

__global__ void repack_w1(const float* __restrict__ W1) {
  const int idx = blockIdx.x * 256 + threadIdx.x;
  if (idx >= NPK * kHid) return;
  const int c = idx >> 9;          // chunk
  const int j = idx & (kHid - 1);  // column
  const int r = RRES + 4 * c;
  float4 v;
  v.x = W1[(size_t)(r + 0) * kHid + j];
  v.y = W1[(size_t)(r + 1) * kHid + j];
  v.z = W1[(size_t)(r + 2) * kHid + j];
  v.w = W1[(size_t)(r + 3) * kHid + j];
  *reinterpret_cast<float4*>(&g_w1p[(size_t)idx * 4]) = v;
}

// wave-uniform broadcast of lane l's copy of v (result lives in an SGPR)
__device__ __forceinline__ float rdl(float v, int l) {
  return __int_as_float(__builtin_amdgcn_readlane(__float_as_int(v), l));
}

__global__
__attribute__((amdgpu_flat_work_group_size(kBlk, kBlk)))
__attribute__((amdgpu_waves_per_eu(2, 2)))
void resrnn_fwd(const float* __restrict__ x, const float* __restrict__ W1,
                const float* __restrict__ b1, const float* __restrict__ W2,
                const float* __restrict__ b2, float* __restrict__ out) {
  // inps: [0..7]=x_t, [8]=s_t, [9..520]=hx_{t-1}  (single batch)
  __shared__ __align__(16) float inps[kInp + 3];
  __shared__ float wlds[RLDS][kHid];   // W1 rows [RAGP, RRES), 144 KB
  __shared__ __align__(16) float red[8];

  const int j = threadIdx.x;           // hidden column 0..511
  const int n = blockIdx.x;            // batch element (1 per block)

  const float b2v = b2[0];
  const float w2j = W2[j];
  const float b1j = b1[j];

  float* const outp = out;                        // (N,L,1) flat
  float* const stor = out + (size_t)kN * kL;      // implied_storage

  const float* xn = x + (size_t)n * kL * kHin;

  const float* const wj  = W1 + j;                // column j, stride kHid
  const float* const wpk = g_w1p + (size_t)j * 4; // packed streamed, stride 2048 floats

  // ---- one-time W1 cache fill: rows [0,RAGP) -> AGPRs ----
  float areg[RAGP];
  #pragma unroll
  for (int r = 0; r < RAGP; ++r) {
    const float v = wj[(size_t)r * kHid];
    asm volatile("v_accvgpr_write_b32 %0, %1" : "=a"(areg[r]) : "v"(v));
  }
  // rows [RAGP, RRES) -> LDS
  for (int r = 0; r < RLDS; ++r) wlds[r][j] = wj[(size_t)(RAGP + r) * kHid];
  // tail row 520 -> one arch VGPR, loaded once
  float wtail = wj[(size_t)(kInp - 1) * kHid];
  asm volatile("" : "+v"(wtail));

  // ---- init: hx = 0, s_0 = x_0[0] ----
  inps[kHin + 1 + j] = 0.f;
  float s = xn[0];
  if (j < kHin) inps[j] = xn[j];
  if (j == 8)   inps[kHin] = s;
  if (j == 0)   stor[(size_t)n * kL] = s;
  __syncthreads();

  for (int t = 0; t < kL; ++t) {
    // ---- lane-distributed copy of inps[0..511]: 2 b128 per wave ----
    const int lane = j & 63;
    const float4 q0 = *reinterpret_cast<const float4*>(&inps[4 * lane]);
    const float4 q1 = *reinterpret_cast<const float4*>(&inps[256 + 4 * lane]);

    float a0 = b1j;   // fma chain A
    float c0 = 0.f;   // fma chain B

    // ---- rows [0, RAGP): weights in AGPRs, inputs via readlane(q0) ----
    // group g covers rows 8g..8g+7 = lanes 2g, 2g+1 of q0
    #pragma unroll
    for (int g = 0; g < NAGRP; ++g) {
      float w0, w1, w2, w3, w4, w5, w6, w7;
      asm volatile(
          "v_accvgpr_read_b32 %0, %8\n\t"
          "v_accvgpr_read_b32 %1, %9\n\t"
          "v_accvgpr_read_b32 %2, %10\n\t"
          "v_accvgpr_read_b32 %3, %11\n\t"
          "v_accvgpr_read_b32 %4, %12\n\t"
          "v_accvgpr_read_b32 %5, %13\n\t"
          "v_accvgpr_read_b32 %6, %14\n\t"
          "v_accvgpr_read_b32 %7, %15"
          : "=v"(w0), "=v"(w1), "=v"(w2), "=v"(w3),
            "=v"(w4), "=v"(w5), "=v"(w6), "=v"(w7)
          : "a"(areg[8 * g + 0]), "a"(areg[8 * g + 1]),
            "a"(areg[8 * g + 2]), "a"(areg[8 * g + 3]),
            "a"(areg[8 * g + 4]), "a"(areg[8 * g + 5]),
            "a"(areg[8 * g + 6]), "a"(areg[8 * g + 7]));
      const int l0 = 2 * g, l1 = 2 * g + 1;
      a0 = fmaf(rdl(q0.x, l0), w0, a0); c0 = fmaf(rdl(q0.y, l0), w1, c0);
      a0 = fmaf(rdl(q0.z, l0), w2, a0); c0 = fmaf(rdl(q0.w, l0), w3, c0);
      a0 = fmaf(rdl(q0.x, l1), w4, a0); c0 = fmaf(rdl(q0.y, l1), w5, c0);
      a0 = fmaf(rdl(q0.z, l1), w6, a0); c0 = fmaf(rdl(q0.w, l1), w7, c0);
    }

    // ---- rows [RAGP, RRES): weights in LDS (lane-consecutive b32, free),
    //      inputs via readlane(q0): rows 128+4u..131+4u = lane 32+u ----
    #pragma unroll 6
    for (int u = 0; u < RLDS / 4; ++u) {
      const int ln = 32 + u;
      const float wa = wlds[4 * u + 0][j];
      const float wb = wlds[4 * u + 1][j];
      const float wc = wlds[4 * u + 2][j];
      const float wd = wlds[4 * u + 3][j];
      a0 = fmaf(rdl(q0.x, ln), wa, a0); c0 = fmaf(rdl(q0.y, ln), wb, c0);
      a0 = fmaf(rdl(q0.z, ln), wc, a0); c0 = fmaf(rdl(q0.w, ln), wd, c0);
    }

    // ---- rows [RRES, 512): streamed packed, inputs via readlane ----
    // chunk c rows 200+4c..203+4c; c<14 -> q0 lane 50+c; c in [14,78) -> q1 lane c-14
    #pragma unroll 7
    for (int c = 0; c < 14; ++c) {
      const float4 wv = *reinterpret_cast<const float4*>(&wpk[(size_t)c * kHid * 4]);
      const int ln = 50 + c;
      a0 = fmaf(rdl(q0.x, ln), wv.x, a0); c0 = fmaf(rdl(q0.y, ln), wv.y, c0);
      a0 = fmaf(rdl(q0.z, ln), wv.z, a0); c0 = fmaf(rdl(q0.w, ln), wv.w, c0);
    }
    #pragma unroll 8
    for (int c = 14; c < 78; ++c) {
      const float4 wv = *reinterpret_cast<const float4*>(&wpk[(size_t)c * kHid * 4]);
      const int ln = c - 14;
      a0 = fmaf(rdl(q1.x, ln), wv.x, a0); c0 = fmaf(rdl(q1.y, ln), wv.y, c0);
      a0 = fmaf(rdl(q1.z, ln), wv.z, a0); c0 = fmaf(rdl(q1.w, ln), wv.w, c0);
    }
    {  // rows 512..519: conventional uniform LDS reads + streamed chunks 78,79
      const float4 w78 = *reinterpret_cast<const float4*>(&wpk[(size_t)78 * kHid * 4]);
      const float4 w79 = *reinterpret_cast<const float4*>(&wpk[(size_t)79 * kHid * 4]);
      const float4 v78 = *reinterpret_cast<const float4*>(&inps[512]);
      const float4 v79 = *reinterpret_cast<const float4*>(&inps[516]);
      a0 = fmaf(v78.x, w78.x, a0); c0 = fmaf(v78.y, w78.y, c0);
      a0 = fmaf(v78.z, w78.z, a0); c0 = fmaf(v78.w, w78.w, c0);
      a0 = fmaf(v79.x, w79.x, a0); c0 = fmaf(v79.y, w79.y, c0);
      a0 = fmaf(v79.z, w79.z, a0); c0 = fmaf(v79.w, w79.w, c0);
    }
    a0 = fmaf(inps[kInp - 1], wtail, a0);  // tail row 520

    const float h = tanhf(a0 + c0);

    // ---- out = hx_new . W2 + b2 : wave shuffle reduce, then LDS combine ----
    float p = h * w2j;
    #pragma unroll
    for (int off = 32; off > 0; off >>= 1) p += __shfl_down(p, off, 64);
    const int wid = j >> 6;
    if ((j & 63) == 0) red[wid] = p;
    __syncthreads();  // barrier A: all inps reads done; red[] populated

    const float4 r0 = *reinterpret_cast<const float4*>(&red[0]);
    const float4 r1 = *reinterpret_cast<const float4*>(&red[4]);
    const float o = (((r0.x + r0.y) + (r0.z + r0.w)) +
                     ((r1.x + r1.y) + (r1.z + r1.w))) + b2v;  // same in all threads
    if (j == 0) outp[(size_t)n * kL + t] = o;

    // ---- stage step t+1: hx, x, s = s + x_{t+1}[0] - out_t ----
    inps[kHin + 1 + j] = h;
    if (t + 1 < kL) {
      const float* xr = xn + (size_t)(t + 1) * kHin;
      s += xr[0] - o;  // replicated identically across threads
      if (j < kHin) inps[j] = xr[j];
      if (j == 8)   inps[kHin] = s;
      if (j == 0)   stor[(size_t)n * kL + t + 1] = s;
    }
    __syncthreads();  // barrier B: next-step inp fully staged
  }
}

extern "C" void kernel_launch(void* const* d_in, const int* in_sizes, int n_in,
                              void* d_out, int out_size, void* d_ws, size_t ws_size,
                              hipStream_t stream) {
  const float* x  = (const float*)d_in[0];
  const float* W1 = (const float*)d_in[1];
  const float* b1 = (const float*)d_in[2];
  const float* W2 = (const float*)d_in[3];
  const float* b2 = (const float*)d_in[4];
  float* out = (float*)d_out;

  // one-time (per launch) repack of streamed W1 rows into float4-per-thread form
  {
    const int total = NPK * kHid;                 // 40960
    dim3 g((total + 255) / 256), b(256);
    hipLaunchKernelGGL(repack_w1, g, b, 0, stream, W1);
  }

  dim3 grid(kN);          // 256 blocks -> 1 batch element per block, all CUs
  dim3 block(kBlk);       // 512 threads = 8 waves
  hipLaunchKernelGGL(resrnn_fwd, grid, block, 0, stream, x, W1, b1, W2, b2, out);
}